// Round 2
// baseline (271.039 us; speedup 1.0000x reference)
//
#include <hip/hip_runtime.h>
#include <hip/hip_bf16.h>

#define NB 256
#define NR 100
#define ND 6168
#define DP 6176            // ND padded to multiple of 32
#define NH 128
#define NC 100
#define CP 112             // NC padded to multiple of 16
#define KSTEP 32
#define NSTEP (DP / KSTEP) // 193

typedef __attribute__((ext_vector_type(8))) __bf16 bf16x8;
typedef __attribute__((ext_vector_type(4))) float f32x4;
typedef __attribute__((ext_vector_type(4))) int i32x4;
typedef __attribute__((ext_vector_type(4))) unsigned int u32x4;

// ---------- prep 1: W1 (ND,NH) f32 -> W1T (NH, DP) bf16, zero-padded ----------
__global__ void prep_w1t(const float* __restrict__ W1, __hip_bfloat16* __restrict__ W1T) {
  __shared__ float tile[KSTEP][NH + 1];
  const int d0 = blockIdx.x * KSTEP;
  const int t = threadIdx.x;
#pragma unroll
  for (int p = 0; p < (KSTEP * NH) / 256; ++p) {
    int idx = p * 256 + t;
    int dd = idx >> 7;
    int h  = idx & 127;
    int d  = d0 + dd;
    tile[dd][h] = (d < ND) ? W1[d * NH + h] : 0.f;
  }
  __syncthreads();
#pragma unroll
  for (int p = 0; p < (KSTEP * NH) / 256; ++p) {
    int idx = p * 256 + t;
    int h  = idx >> 5;
    int dd = idx & 31;
    W1T[h * DP + d0 + dd] = __float2bfloat16(tile[dd][h]);
  }
}

// ---------- prep 2: W2 (NH,NC) f32 -> W2T (CP, NH) bf16, zero rows for c>=NC ----------
__global__ void prep_w2t(const float* __restrict__ W2, __hip_bfloat16* __restrict__ W2T) {
  int t = blockIdx.x * 256 + threadIdx.x;
  if (t < CP * NH) {
    int c = t >> 7;
    int h = t & 127;
    float v = (c < NC) ? W2[h * NC + c] : 0.f;
    W2T[t] = __float2bfloat16(v);
  }
}

// ---------- main fused kernel: one block per b, 512 threads (8 waves, 2/SIMD) ----------
// LDS layout (bytes):
//   [0, 12352)        xpair: 3088 dwords, (x[2i]&1) | (x[2i+1]&1)<<16
//   [12352, 94272)    4 buffers x 20480: A [128 rows x 80B] then B [128 rows x 80B]
//   epilogue overlay at 12352: h_tile [128][136] bf16 (34816 B), partial [8][112] f32
__launch_bounds__(512, 1)
__global__ void fused_main(const int* __restrict__ x,
                           const int* __restrict__ noise,
                           const __hip_bfloat16* __restrict__ W1T,
                           const float* __restrict__ b1,
                           const __hip_bfloat16* __restrict__ W2T,
                           const float* __restrict__ b2,
                           float* __restrict__ out) {
  __shared__ __align__(16) char lds[94272];
  unsigned int* xpair = (unsigned int*)lds;
  char* const bufbase = lds + 12352;
  char* const BF0 = bufbase;
  char* const BF1 = bufbase + 20480;
  char* const BF2 = bufbase + 40960;
  char* const BF3 = bufbase + 61440;

  const int tid  = threadIdx.x;
  const int lane = tid & 63;
  const int w    = tid >> 6;        // wave 0..7
  const int wm   = w >> 2;          // 0..1 : row half
  const int wn   = w & 3;           // 0..3 : col quarter
  const int lq   = lane >> 4;
  const int lm   = lane & 15;
  const int b    = blockIdx.x;

  const int r  = tid >> 2;          // staging row 0..127
  const int kc = tid & 3;           // k-octet within 32-wide chunk
  const bool rvalid = (r < NR);

  const int*  nbase = noise + (long)b * NR * ND + (long)r * ND + kc * 8;
  const char* bsrc  = (const char*)W1T + (long)r * DP * 2 + kc * 16;

  f32x4 acc[4][2] = {};

  auto ISSUE = [&](int s, i32x4* ra, i32x4* rb) {
    const int k0 = s * KSTEP + kc * 8;
    i32x4 z = {0, 0, 0, 0};
    ra[0] = (rvalid && k0 + 4 <= ND) ? *(const i32x4*)(nbase + (long)s * KSTEP)     : z;
    ra[1] = (rvalid && k0 + 8 <= ND) ? *(const i32x4*)(nbase + (long)s * KSTEP + 4) : z;
    rb[0] = *(const i32x4*)(bsrc + (long)s * 64);
  };

  auto STORE = [&](int s, const i32x4* ra, const i32x4* rb, char* buf) {
    u32x4 xp = *(const u32x4*)(xpair + s * 16 + kc * 4);
    unsigned int pk[4];
#pragma unroll
    for (int j = 0; j < 4; ++j) {
      unsigned n0 = (unsigned)ra[j >> 1][(j & 1) * 2];
      unsigned n1 = (unsigned)ra[j >> 1][(j & 1) * 2 + 1];
      pk[j] = ((n0 | (n1 << 16)) ^ xp[j]) * 0x3F80u;
    }
    u32x4 t = {pk[0], pk[1], pk[2], pk[3]};
    *(u32x4*)(buf + r * 80 + kc * 16) = t;                 // A (bf16)
    *(i32x4*)(buf + 10240 + r * 80 + kc * 16) = rb[0];     // B (bf16 raw)
  };

  auto COMPUTE = [&](const char* buf) {
    const char* A  = buf;
    const char* Bb = buf + 10240;
    bf16x8 bf0 = *(const bf16x8*)(Bb + (wn * 32 + lm) * 80 + lq * 16);
    bf16x8 bf1 = *(const bf16x8*)(Bb + (wn * 32 + 16 + lm) * 80 + lq * 16);
#pragma unroll
    for (int mf = 0; mf < 4; ++mf) {
      bf16x8 af = *(const bf16x8*)(A + (wm * 64 + mf * 16 + lm) * 80 + lq * 16);
      acc[mf][0] = __builtin_amdgcn_mfma_f32_16x16x32_bf16(af, bf0, acc[mf][0], 0, 0, 0);
      acc[mf][1] = __builtin_amdgcn_mfma_f32_16x16x32_bf16(af, bf1, acc[mf][1], 0, 0, 0);
    }
  };

  i32x4 raA[2], rbA[1], raB[2], rbB[1];

  // ---- prologue ----
  ISSUE(0, raA, rbA);
  ISSUE(1, raB, rbB);
  {
    const int* xb = x + b * ND;
    for (int i = tid; i < DP / 2; i += 512) {
      unsigned p = 0;
      if (2 * i < ND) {
        int2 v = *(const int2*)(xb + 2 * i);
        p = ((unsigned)v.x & 1u) | (((unsigned)v.y & 1u) << 16);
      }
      xpair[i] = p;
    }
  }
  __syncthreads();
  STORE(0, raA, rbA, BF0);
  ISSUE(2, raA, rbA);
  STORE(1, raB, rbB, BF1);
  __syncthreads();

  // ---- main loop: unroll 4, slots A/B alternate (even tiles->A, odd->B) ----
  for (int s = 0; s < NSTEP; s += 4) {
    {
      COMPUTE(BF0);
      if (s + 3 < NSTEP) ISSUE(s + 3, raB, rbB);
      if (s + 2 < NSTEP) STORE(s + 2, raA, rbA, BF2);
      __syncthreads();
    }
    if (s + 1 < NSTEP) {
      COMPUTE(BF1);
      if (s + 4 < NSTEP) ISSUE(s + 4, raA, rbA);
      if (s + 3 < NSTEP) STORE(s + 3, raB, rbB, BF3);
      __syncthreads();
    }
    if (s + 2 < NSTEP) {
      COMPUTE(BF2);
      if (s + 5 < NSTEP) ISSUE(s + 5, raB, rbB);
      if (s + 4 < NSTEP) STORE(s + 4, raA, rbA, BF0);
      __syncthreads();
    }
    if (s + 3 < NSTEP) {
      COMPUTE(BF3);
      if (s + 6 < NSTEP) ISSUE(s + 6, raA, rbA);
      if (s + 5 < NSTEP) STORE(s + 5, raB, rbB, BF1);
      __syncthreads();
    }
  }
  __syncthreads();

  // ---------------- epilogue ----------------
  __hip_bfloat16* h_tile = (__hip_bfloat16*)(lds + 12352);   // [128][136]
  float* partial = (float*)(lds + 12352 + 34816);            // [8][112]

#pragma unroll
  for (int nf = 0; nf < 2; ++nf) {
    int hcol = wn * 32 + nf * 16 + lm;
    float bb = b1[hcol];
#pragma unroll
    for (int mf = 0; mf < 4; ++mf) {
#pragma unroll
      for (int rg = 0; rg < 4; ++rg) {
        int m = wm * 64 + mf * 16 + lq * 4 + rg;
        h_tile[m * 136 + hcol] = __float2bfloat16(tanhf(acc[mf][nf][rg] + bb));
      }
    }
  }
  __syncthreads();

  // layer 2: wave w -> rows [w*16, w*16+16)
  f32x4 acc2[7] = {};
#pragma unroll
  for (int ks = 0; ks < 4; ++ks) {
    bf16x8 a2 = *(const bf16x8*)((const unsigned short*)h_tile + (w * 16 + lm) * 136 + ks * 32 + lq * 8);
#pragma unroll
    for (int nf = 0; nf < 7; ++nf) {
      bf16x8 b2f = *(const bf16x8*)((const unsigned short*)W2T + (nf * 16 + lm) * NH + ks * 32 + lq * 8);
      acc2[nf] = __builtin_amdgcn_mfma_f32_16x16x32_bf16(a2, b2f, acc2[nf], 0, 0, 0);
    }
  }

#pragma unroll
  for (int nf = 0; nf < 7; ++nf) {
    float ssum = 0.f;
#pragma unroll
    for (int rg = 0; rg < 4; ++rg) {
      int m = w * 16 + lq * 4 + rg;
      ssum += (m < NR) ? acc2[nf][rg] : 0.f;
    }
    ssum += __shfl_xor(ssum, 16, 64);
    ssum += __shfl_xor(ssum, 32, 64);
    if (lq == 0) partial[w * 112 + nf * 16 + lm] = ssum;
  }
  __syncthreads();

  if (tid < NC) {
    float fsum = 0.f;
#pragma unroll
    for (int p = 0; p < 8; ++p) fsum += partial[p * 112 + tid];
    out[b * NC + tid] = fsum * (1.f / NR) + b2[tid];
  }
}

extern "C" void kernel_launch(void* const* d_in, const int* in_sizes, int n_in,
                              void* d_out, int out_size, void* d_ws, size_t ws_size,
                              hipStream_t stream) {
  (void)in_sizes; (void)n_in; (void)out_size; (void)ws_size;
  const int* x     = (const int*)d_in[0];
  const int* noise = (const int*)d_in[1];
  const float* W1  = (const float*)d_in[2];
  const float* b1  = (const float*)d_in[3];
  const float* W2  = (const float*)d_in[4];
  const float* b2  = (const float*)d_in[5];
  float* out = (float*)d_out;

  __hip_bfloat16* W1T = (__hip_bfloat16*)d_ws;
  __hip_bfloat16* W2T = (__hip_bfloat16*)((char*)d_ws + (size_t)NH * DP * 2);

  prep_w1t<<<DP / KSTEP, 256, 0, stream>>>(W1, W1T);
  prep_w2t<<<(CP * NH + 255) / 256, 256, 0, stream>>>(W2, W2T);
  fused_main<<<NB, 512, 0, stream>>>(x, noise, W1T, b1, W2T, b2, out);
}

// Round 3
// 224.799 us; speedup vs baseline: 1.2057x; 1.2057x over previous
//
#include <hip/hip_runtime.h>
#include <hip/hip_bf16.h>

#define NB 256
#define NR 100
#define ND 6168
#define DP 6176            // ND padded to multiple of 32
#define NH 128
#define NC 100
#define CP 112             // NC padded to multiple of 16
#define KSTEP 32
#define NSTEP (DP / KSTEP) // 193

typedef __attribute__((ext_vector_type(8))) __bf16 bf16x8;
typedef __attribute__((ext_vector_type(4))) float f32x4;
typedef __attribute__((ext_vector_type(4))) int i32x4;
typedef __attribute__((ext_vector_type(4))) unsigned int u32x4;

// Non-draining barrier: LDS ordering only; global loads stay in flight (T4).
#define BAR() do { asm volatile("s_waitcnt lgkmcnt(0)" ::: "memory"); \
                   __builtin_amdgcn_s_barrier(); } while (0)

// ---------- prep 1: W1 (ND,NH) f32 -> W1T (NH, DP) bf16, zero-padded ----------
__global__ void prep_w1t(const float* __restrict__ W1, __hip_bfloat16* __restrict__ W1T) {
  __shared__ float tile[KSTEP][NH + 1];
  const int d0 = blockIdx.x * KSTEP;
  const int t = threadIdx.x;
#pragma unroll
  for (int p = 0; p < (KSTEP * NH) / 256; ++p) {
    int idx = p * 256 + t;
    int dd = idx >> 7;
    int h  = idx & 127;
    int d  = d0 + dd;
    tile[dd][h] = (d < ND) ? W1[d * NH + h] : 0.f;
  }
  __syncthreads();
#pragma unroll
  for (int p = 0; p < (KSTEP * NH) / 256; ++p) {
    int idx = p * 256 + t;
    int h  = idx >> 5;
    int dd = idx & 31;
    W1T[h * DP + d0 + dd] = __float2bfloat16(tile[dd][h]);
  }
}

// ---------- prep 2: W2 (NH,NC) f32 -> W2T (CP, NH) bf16, zero rows for c>=NC ----------
__global__ void prep_w2t(const float* __restrict__ W2, __hip_bfloat16* __restrict__ W2T) {
  int t = blockIdx.x * 256 + threadIdx.x;
  if (t < CP * NH) {
    int c = t >> 7;
    int h = t & 127;
    float v = (c < NC) ? W2[h * NC + c] : 0.f;
    W2T[t] = __float2bfloat16(v);
  }
}

// ---------- main fused kernel: one block per b, 256 threads (4 waves) ----------
// LDS (bytes):
//   [0, 12352)      xpair: 3088 dwords, (x[2i]&1) | (x[2i+1]&1)<<16
//   [12352, 32832)  BF0: A [128 x 80B] then B [128 x 80B]
//   [32832, 53312)  BF1
//   epilogue overlay at 0: h_tile [128][136] bf16 (34816 B); partial [8][112] f32 at 34816
__launch_bounds__(256, 1)
__global__ void fused_main(const int* __restrict__ x,
                           const int* __restrict__ noise,
                           const __hip_bfloat16* __restrict__ W1T,
                           const float* __restrict__ b1,
                           const __hip_bfloat16* __restrict__ W2T,
                           const float* __restrict__ b2,
                           float* __restrict__ out) {
  __shared__ __align__(16) char lds[53312];
  unsigned int* xpair = (unsigned int*)lds;
  char* const BF0 = lds + 12352;
  char* const BF1 = BF0 + 20480;

  const int tid  = threadIdx.x;
  const int lane = tid & 63;
  const int w    = tid >> 6;       // wave 0..3
  const int lq   = lane >> 4;
  const int lm   = lane & 15;
  const int b    = blockIdx.x;

  const int r  = tid >> 1;         // staging row 0..127
  const int kh = tid & 1;          // 16-k half within 32-wide chunk
  const bool rvalid = (r < NR);

  const int*  nbase = noise + (long)b * NR * ND + (long)r * ND + kh * 16;
  const char* bsrc  = (const char*)W1T + (long)r * DP * 2 + kh * 32;

  f32x4 acc[8][2] = {};

  auto ISSUE = [&](int s, i32x4* ra, i32x4* rb) {
    i32x4 z = {0, 0, 0, 0};
    const long o = (long)s * KSTEP;
#pragma unroll
    for (int j = 0; j < 4; ++j) {
      int k0 = s * KSTEP + kh * 16 + j * 4;
      ra[j] = (rvalid && k0 + 4 <= ND) ? *(const i32x4*)(nbase + o + j * 4) : z;
    }
    rb[0] = *(const i32x4*)(bsrc + o * 2);
    rb[1] = *(const i32x4*)(bsrc + o * 2 + 16);
  };

  auto STORE = [&](int s, const i32x4* ra, const i32x4* rb, char* buf) {
    u32x4 xp0 = *(const u32x4*)(xpair + s * 16 + kh * 8);
    u32x4 xp1 = *(const u32x4*)(xpair + s * 16 + kh * 8 + 4);
    unsigned pk[8];
#pragma unroll
    for (int p = 0; p < 8; ++p) {
      unsigned n0 = (unsigned)ra[p >> 1][(p & 1) * 2];
      unsigned n1 = (unsigned)ra[p >> 1][(p & 1) * 2 + 1];
      unsigned xv = (p < 4) ? xp0[p] : xp1[p - 4];
      pk[p] = ((n0 | (n1 << 16)) ^ xv) * 0x3F80u;
    }
    u32x4 t0 = {pk[0], pk[1], pk[2], pk[3]};
    u32x4 t1 = {pk[4], pk[5], pk[6], pk[7]};
    *(u32x4*)(buf + r * 80 + kh * 32)          = t0;
    *(u32x4*)(buf + r * 80 + kh * 32 + 16)     = t1;
    *(i32x4*)(buf + 10240 + r * 80 + kh * 32)      = rb[0];
    *(i32x4*)(buf + 10240 + r * 80 + kh * 32 + 16) = rb[1];
  };

  auto COMPUTE = [&](const char* buf) {
    const char* Bb = buf + 10240;
    bf16x8 bf0 = *(const bf16x8*)(Bb + (w * 32 + lm) * 80 + lq * 16);
    bf16x8 bf1 = *(const bf16x8*)(Bb + (w * 32 + 16 + lm) * 80 + lq * 16);
#pragma unroll
    for (int mf = 0; mf < 8; ++mf) {
      bf16x8 af = *(const bf16x8*)(buf + (mf * 16 + lm) * 80 + lq * 16);
      acc[mf][0] = __builtin_amdgcn_mfma_f32_16x16x32_bf16(af, bf0, acc[mf][0], 0, 0, 0);
      acc[mf][1] = __builtin_amdgcn_mfma_f32_16x16x32_bf16(af, bf1, acc[mf][1], 0, 0, 0);
    }
  };

  i32x4 raA[4], rbA[2], raB[4], rbB[2];

  // ---- prologue ----
  ISSUE(0, raA, rbA);
  ISSUE(1, raB, rbB);
  {
    const int* xb = x + b * ND;
    for (int i = tid; i < DP / 2; i += 256) {
      unsigned p = 0;
      if (2 * i + 1 < ND) {
        int2 v = *(const int2*)(xb + 2 * i);
        p = ((unsigned)v.x & 1u) | (((unsigned)v.y & 1u) << 16);
      }
      xpair[i] = p;
    }
  }
  BAR();
  STORE(0, raA, rbA, BF0);
  ISSUE(2, raA, rbA);
  BAR();

  // ---- main loop: even tiles -> BF0/slotA, odd tiles -> BF1/slotB ----
  for (int s = 0; s < NSTEP; s += 2) {
    COMPUTE(BF0);
    if (s + 1 < NSTEP) STORE(s + 1, raB, rbB, BF1);
    if (s + 3 < NSTEP) ISSUE(s + 3, raB, rbB);
    BAR();
    if (s + 1 < NSTEP) {
      COMPUTE(BF1);
      if (s + 2 < NSTEP) STORE(s + 2, raA, rbA, BF0);
      if (s + 4 < NSTEP) ISSUE(s + 4, raA, rbA);
      BAR();
    }
  }

  // ---------------- epilogue ----------------
  __hip_bfloat16* h_tile = (__hip_bfloat16*)lds;        // [128][136]
  float* partial = (float*)(lds + 34816);                // [8][112]

#pragma unroll
  for (int nf = 0; nf < 2; ++nf) {
    int hcol = w * 32 + nf * 16 + lm;
    float bb = b1[hcol];
#pragma unroll
    for (int mf = 0; mf < 8; ++mf) {
#pragma unroll
      for (int rg = 0; rg < 4; ++rg) {
        int m = mf * 16 + lq * 4 + rg;
        h_tile[m * 136 + hcol] = __float2bfloat16(tanhf(acc[mf][nf][rg] + bb));
      }
    }
  }
  __syncthreads();

  // layer 2: wave w -> rows [w*32, w*32+32)
  f32x4 acc2[2][7] = {};
#pragma unroll
  for (int ks = 0; ks < 4; ++ks) {
    bf16x8 a2_0 = *(const bf16x8*)((const unsigned short*)h_tile + (w * 32 + lm) * 136 + ks * 32 + lq * 8);
    bf16x8 a2_1 = *(const bf16x8*)((const unsigned short*)h_tile + (w * 32 + 16 + lm) * 136 + ks * 32 + lq * 8);
#pragma unroll
    for (int nf = 0; nf < 7; ++nf) {
      bf16x8 b2f = *(const bf16x8*)((const unsigned short*)W2T + (nf * 16 + lm) * NH + ks * 32 + lq * 8);
      acc2[0][nf] = __builtin_amdgcn_mfma_f32_16x16x32_bf16(a2_0, b2f, acc2[0][nf], 0, 0, 0);
      acc2[1][nf] = __builtin_amdgcn_mfma_f32_16x16x32_bf16(a2_1, b2f, acc2[1][nf], 0, 0, 0);
    }
  }

#pragma unroll
  for (int mf2 = 0; mf2 < 2; ++mf2) {
    int mbase = w * 32 + mf2 * 16 + lq * 4;
#pragma unroll
    for (int nf = 0; nf < 7; ++nf) {
      float ssum = 0.f;
#pragma unroll
      for (int rg = 0; rg < 4; ++rg) {
        int m = mbase + rg;
        ssum += (m < NR) ? acc2[mf2][nf][rg] : 0.f;
      }
      ssum += __shfl_xor(ssum, 16, 64);
      ssum += __shfl_xor(ssum, 32, 64);
      if (lq == 0) partial[(w * 2 + mf2) * 112 + nf * 16 + lm] = ssum;
    }
  }
  __syncthreads();

  if (tid < NC) {
    float fsum = 0.f;
#pragma unroll
    for (int p = 0; p < 8; ++p) fsum += partial[p * 112 + tid];
    out[b * NC + tid] = fsum * (1.f / NR) + b2[tid];
  }
}

extern "C" void kernel_launch(void* const* d_in, const int* in_sizes, int n_in,
                              void* d_out, int out_size, void* d_ws, size_t ws_size,
                              hipStream_t stream) {
  (void)in_sizes; (void)n_in; (void)out_size; (void)ws_size;
  const int* x     = (const int*)d_in[0];
  const int* noise = (const int*)d_in[1];
  const float* W1  = (const float*)d_in[2];
  const float* b1  = (const float*)d_in[3];
  const float* W2  = (const float*)d_in[4];
  const float* b2  = (const float*)d_in[5];
  float* out = (float*)d_out;

  __hip_bfloat16* W1T = (__hip_bfloat16*)d_ws;
  __hip_bfloat16* W2T = (__hip_bfloat16*)((char*)d_ws + (size_t)NH * DP * 2);

  prep_w1t<<<DP / KSTEP, 256, 0, stream>>>(W1, W1T);
  prep_w2t<<<(CP * NH + 255) / 256, 256, 0, stream>>>(W2, W2T);
  fused_main<<<NB, 256, 0, stream>>>(x, noise, W1T, b1, W2T, b2, out);
}